// Round 18
// baseline (487.460 us; speedup 1.0000x reference)
//
#include <hip/hip_runtime.h>
#include <cstdint>
#include <cstddef>

#define S_LEN 4096
#define DVEC  1024
#define DH    256

typedef __attribute__((ext_vector_type(8))) short short8;
typedef __attribute__((ext_vector_type(4))) float f32x4;
typedef __attribute__((ext_vector_type(4))) unsigned short ushort4v;

__device__ __forceinline__ unsigned short f2bf(float f) {
  unsigned u = __builtin_bit_cast(unsigned, f);
  u += 0x7FFFu + ((u >> 16) & 1u);          // round-to-nearest-even
  return (unsigned short)(u >> 16);
}

__device__ __forceinline__ void gl2lds16(const void* g, void* lds) {
  __builtin_amdgcn_global_load_lds(
      (const __attribute__((address_space(1))) unsigned int*)g,
      (__attribute__((address_space(3))) unsigned int*)lds, 16, 0, 0);
}

__device__ __forceinline__ void cbar() { asm volatile("" ::: "memory"); }

// BAR1: LDS visibility only (P writes -> PV reads). No vmem hazard crosses
// it (gl2lds targets buf^1, read only after BAR2; V/mask are reg loads,
// auto-guarded by compiler dep-waits).
__device__ __forceinline__ void bar_lgkm() {
  asm volatile("s_waitcnt lgkmcnt(0)" ::: "memory");
  __builtin_amdgcn_s_barrier();
  asm volatile("" ::: "memory");
}
// BAR2: drains everything. stageK(t+1)+mask(t+1) were issued at the TOP of
// this iteration (~2000cy earlier) so this wait is ~free — and immune to
// instruction-order surprises (no manual vmcnt counting).
__device__ __forceinline__ void bar_vm0() {
  asm volatile("s_waitcnt vmcnt(0) lgkmcnt(0)" ::: "memory");
  __builtin_amdgcn_s_barrier();
  asm volatile("" ::: "memory");
}

// ---------------------------------------------------------------------------
// Kernel 1: weights f32 -> bf16 (wq pre-scaled by 1/sqrt(DH)=1/16).
// ---------------------------------------------------------------------------
__global__ void wcvt_kernel(const float* __restrict__ wq,
                            const float* __restrict__ wk,
                            const float* __restrict__ wv,
                            unsigned short* __restrict__ wbf) {
  int t   = blockIdx.x * 256 + threadIdx.x;
  int idx = t * 4;
  int m   = idx >> 18;
  int off = idx & 262143;
  const float* src = (m == 0) ? wq : (m == 1) ? wk : wv;
  float scale = (m == 0) ? 0.0625f : 1.0f;
  f32x4 v = *(const f32x4*)(src + off);
  ushort4v o;
  o.x = f2bf(v.x * scale);
  o.y = f2bf(v.y * scale);
  o.z = f2bf(v.z * scale);
  o.w = f2bf(v.w * scale);
  *(ushort4v*)(wbf + idx) = o;
}

// ---------------------------------------------------------------------------
// Kernel 2: projection GEMM (unchanged). C = x * W^T + b -> bf16; z==2 -> V^T.
// ---------------------------------------------------------------------------
__global__ void proj_kernel(const float* __restrict__ xq,
                            const float* __restrict__ xk,
                            const float* __restrict__ xv,
                            const unsigned short* __restrict__ wbf,
                            const float* __restrict__ bq,
                            const float* __restrict__ bk,
                            const float* __restrict__ bv,
                            unsigned short* __restrict__ qbf,
                            unsigned short* __restrict__ kbf,
                            unsigned short* __restrict__ vtbf) {
  const int tid  = threadIdx.x;
  const int lane = tid & 63;
  const int w    = tid >> 6;
  const int z    = blockIdx.z;
  const int m0   = blockIdx.x * 64;

  const float* x = (z == 0) ? xq : (z == 1) ? xk : xv;
  const unsigned short* wz = wbf + (size_t)z * (DH * DVEC);
  const float* bias = (z == 0) ? bq : (z == 1) ? bk : bv;
  const float bscale = (z == 0) ? 0.0625f : 1.0f;

  __shared__ float At[2][64 * 32];

  f32x4 zero = {0.f, 0.f, 0.f, 0.f};
  f32x4 acc[4][4];
#pragma unroll
  for (int i = 0; i < 4; ++i)
#pragma unroll
    for (int j = 0; j < 4; ++j) acc[i][j] = zero;

  auto stage = [&](int kt, int buf) {
    char* dstb = (char*)&At[buf][0] + w * 2048;
#pragma unroll
    for (int i = 0; i < 2; ++i) {
      int lin  = w * 2048 + i * 1024 + lane * 16;
      int row  = lin >> 7;
      int scol = (lin ^ ((row & 7) << 4)) & 127;
      gl2lds16((const char*)x + ((size_t)(m0 + row) * DVEC + kt * 32) * 4 + scol,
               dstb + i * 1024);
    }
  };

  stage(0, 0);
  __syncthreads();

  for (int kt = 0; kt < 32; ++kt) {
    const int buf = kt & 1;
    if (kt + 1 < 32) stage(kt + 1, buf ^ 1);

    short8 bfr[4];
#pragma unroll
    for (int cf = 0; cf < 4; ++cf) {
      int h = w * 64 + cf * 16 + (lane & 15);
      int d = kt * 32 + (lane >> 4) * 8;
      bfr[cf] = *(const short8*)(wz + (size_t)h * DVEC + d);
    }
    const char* ab = (const char*)&At[buf][0];
#pragma unroll
    for (int rf = 0; rf < 4; ++rf) {
      int row = rf * 16 + (lane & 15);
      int c0  = row * 128 + (lane >> 4) * 32;
      int sw  = (row & 7) << 4;
      f32x4 v0 = *(const f32x4*)(ab + (c0 ^ sw));
      f32x4 v1 = *(const f32x4*)(ab + ((c0 + 16) ^ sw));
      short8 af;
      af[0] = (short)f2bf(v0.x); af[1] = (short)f2bf(v0.y);
      af[2] = (short)f2bf(v0.z); af[3] = (short)f2bf(v0.w);
      af[4] = (short)f2bf(v1.x); af[5] = (short)f2bf(v1.y);
      af[6] = (short)f2bf(v1.z); af[7] = (short)f2bf(v1.w);
#pragma unroll
      for (int cf = 0; cf < 4; ++cf)
        acc[rf][cf] = __builtin_amdgcn_mfma_f32_16x16x32_bf16(af, bfr[cf], acc[rf][cf], 0, 0, 0);
    }
    __syncthreads();
  }

  float bvv[4];
#pragma unroll
  for (int cf = 0; cf < 4; ++cf)
    bvv[cf] = bias[w * 64 + cf * 16 + (lane & 15)] * bscale;

  if (z < 2) {
    unsigned short* o = (z == 0) ? qbf : kbf;
#pragma unroll
    for (int rf = 0; rf < 4; ++rf)
#pragma unroll
      for (int cf = 0; cf < 4; ++cf)
#pragma unroll
        for (int r = 0; r < 4; ++r) {
          int m = m0 + rf * 16 + (lane >> 4) * 4 + r;
          int h = w * 64 + cf * 16 + (lane & 15);
          o[(size_t)m * DH + h] = f2bf(acc[rf][cf][r] + bvv[cf]);
        }
  } else {
    int bb = m0 >> 12;
    int sl = m0 & 4095;
#pragma unroll
    for (int rf = 0; rf < 4; ++rf)
#pragma unroll
      for (int cf = 0; cf < 4; ++cf) {
        int s = sl + rf * 16 + (lane >> 4) * 4;
        int h = w * 64 + cf * 16 + (lane & 15);
        ushort4v o;
        o.x = f2bf(acc[rf][cf][0] + bvv[cf]);
        o.y = f2bf(acc[rf][cf][1] + bvv[cf]);
        o.z = f2bf(acc[rf][cf][2] + bvv[cf]);
        o.w = f2bf(acc[rf][cf][3] + bvv[cf]);
        *(ushort4v*)(vtbf + ((size_t)(bb * DH + h)) * S_LEN + s) = o;
      }
  }
}

// ---------------------------------------------------------------------------
// Kernel 3: fused masked attention. 512 blocks x 512 thr, 32 q rows, KVB=64.
// LDS 70144 B + grid 512 -> TRUE 2 blocks/CU (4 waves/SIMD).
//   QK role:  kvs = w&3 (16-kv slice), qh = w>>2 (16 q rows)
//             8 K ds_reads -> 8 MFMAs (2 partial chains).
//   PV role:  qp = w>>2 (16 q rows), hs = w&3 (64 h cols = 4 h-frags)
//             [r17 bug fixed: wave covers 4 h-frags -> full 32q x 256h]
//             P via conflict-free chunk microlayout (lane*16 reads,
//             sigma-involution row' = r*4+g), V DIRECT global->regs,
//             both kv-halves x 4 hf at iteration top (QK hides L2 latency).
// K gl2lds dbuf 2x32KB. BAR1 = lgkm-only; BAR2 = vmcnt(0) (targets issued a
// full phase earlier -> ~free, no manual-count hazard).
// Softmax without max (scores bounded; exp(0)=1 = reference fill-0).
// LDS: K 2x32KB | P 4KB | l 512B = 70144 bytes.
// ---------------------------------------------------------------------------
__global__ void __launch_bounds__(512, 2)
attn_kernel(const unsigned short* __restrict__ qbf,
            const unsigned short* __restrict__ kbf,
            const unsigned short* __restrict__ vtbf,
            const int* __restrict__ mask,
            float* __restrict__ out) {
  const int tid  = threadIdx.x;
  const int lane = tid & 63;
  const int w    = tid >> 6;          // 0..7
  const int j    = lane & 15;
  const int g    = lane >> 4;

  const int kvs = w & 3;              // QK role: 16-kv slice
  const int qh  = w >> 2;             // QK role: 16-q group
  const int qp  = w >> 2;             // PV role: 16-q group
  const int hs  = w & 3;              // PV role: 64-h slice (4 h-frags)

  // XCD-aware decode (blocks on one XCD share a batch -> K/V L2-resident)
  const int bx = blockIdx.x;
  const int x  = bx & 7;
  const int b  = x >> 1;
  const int qt = (bx >> 3) * 2 + (x & 1);   // 0..127
  const int m0 = qt * 32;

  __shared__ char sbuf[70144];
  // K: buf*32768 [0,65536) ; P: 65536 [4KB) ; lbuf: 69632 [32][4] f32
  float* lbuf = (float*)(sbuf + 69632);

  // ---- Q fragments (QK role): rows qh*16 + j, 8 k-chunks  [32 VGPR]
  short8 qreg[8];
  {
    const unsigned short* qrow =
        qbf + ((size_t)(b * S_LEN + m0 + qh * 16 + j)) * DH + g * 8;
#pragma unroll
    for (int kc = 0; kc < 8; ++kc) qreg[kc] = *(const short8*)(qrow + kc * 32);
  }

  f32x4 zero = {0.f, 0.f, 0.f, 0.f};
  f32x4 acc[4];                        // PV output: 16q x 64h (4 h-frags)
#pragma unroll
  for (int hf = 0; hf < 4; ++hf) acc[hf] = zero;
  float lrow[4] = {0.f, 0.f, 0.f, 0.f};

  // mask base (raw int32): q = m0 + qh*16 + g*4 + r ; kv = t*64 + kvs*16 + j
  const int* mb = mask + ((size_t)(b * S_LEN + m0 + qh * 16 + g * 4)) * S_LEN
                  + kvs * 16 + j;
  int mcur, mnext;

  // ---- K staging: 32 chunks of 1KB, 4 per wave, wave-uniform LDS dst.
  // Chunk rid = ks*8 + kc holds (lane-linear): K[t*64+ks*16+(l&15)][kc*32+(l>>4)*8..]
  auto stageK = [&](int t1, int bufbase) {
    const char* src = (const char*)kbf + ((size_t)(b * S_LEN + t1 * 64)) * 512;
    char* dst = sbuf + bufbase + w * 4096;
#pragma unroll
    for (int i = 0; i < 4; ++i) {
      int rid = w * 4 + i;
      int ks  = rid >> 3;
      int kc  = rid & 7;
      gl2lds16(src + (size_t)(ks * 16 + j) * 512 + kc * 64 + g * 16, dst + i * 1024);
    }
  };

  // V direct base (PV role): V^T row = b*DH + hs*64 + hf*16 + j
  const unsigned short* vbase =
      vtbf + ((size_t)(b * DH + hs * 64 + j)) * S_LEN + g * 8;

  // P write base: chunk = qh*2 + (kvs>>1); within-chunk byte =
  // (kvs&1)*512 + (j>>3)*256 + (row' = r*4+g)*16 + (j&7)*2
  const int pwbase = 65536 + (qh * 2 + (kvs >> 1)) * 1024 + (kvs & 1) * 512
                   + (j >> 3) * 256 + (j & 7) * 2;

  auto loadmask = [&](int t1) -> int {
    int mm = 0;
#pragma unroll
    for (int r = 0; r < 4; ++r)
      mm |= (mb[(size_t)r * S_LEN + t1 * 64] != 0) << r;
    return mm;
  };

  // prologue
  stageK(0, 0);
  mcur = loadmask(0);
  __syncthreads();

  const int NT = S_LEN / 64;   // 64
  for (int t = 0; t < NT; ++t) {
    const int bufb = (t & 1) * 32768;

    // ---- V(t) -> regs: both kv-halves x 4 h-frags (QK hides L2 latency)
    short8 va[4], vb[4];
    {
      const unsigned short* vt = vbase + t * 64;
#pragma unroll
      for (int hf = 0; hf < 4; ++hf) {
        va[hf] = *(const short8*)(vt + (size_t)(hf * 16) * S_LEN);
        vb[hf] = *(const short8*)(vt + (size_t)(hf * 16) * S_LEN + 32);
      }
    }
    cbar();

    if (t + 1 < NT) {
      stageK(t + 1, bufb ^ 32768);     // gl2lds: drained at BAR2
      cbar();
      mnext = loadmask(t + 1);
    } else {
      mnext = 0;
    }
    cbar();

    // ---- QK(t): 16q x 16kv, K=256 -> 8 MFMAs as 2 partial chains
    const char* kb = sbuf + bufb + kvs * 8192;
    f32x4 sA = zero, sB = zero;
    __builtin_amdgcn_s_setprio(1);
#pragma unroll
    for (int kc = 0; kc < 8; kc += 2) {
      short8 k0 = *(const short8*)(kb + kc * 1024 + lane * 16);
      short8 k1 = *(const short8*)(kb + (kc + 1) * 1024 + lane * 16);
      sA = __builtin_amdgcn_mfma_f32_16x16x32_bf16(qreg[kc], k0, sA, 0, 0, 0);
      sB = __builtin_amdgcn_mfma_f32_16x16x32_bf16(qreg[kc + 1], k1, sB, 0, 0, 0);
    }
    __builtin_amdgcn_s_setprio(0);

    // ---- softmax (no max): p = mask ? exp(s) : 1 ; write P (bf16)
#pragma unroll
    for (int r = 0; r < 4; ++r) {
      float sv = sA[r] + sB[r];
      sv = ((mcur >> r) & 1) ? sv : 0.0f;
      float e = __expf(sv);
      lrow[r] += e;
      *(unsigned short*)(sbuf + pwbase + (r * 4 + g) * 16) = f2bf(e);
    }

    bar_lgkm();                        // BAR1: P visible; prefetch in flight

    // ---- PV(t): P from LDS (conflict-free lane*16), V from regs
    const char* pbase = sbuf + 65536 + qp * 2048;
    {
      short8 pf0 = *(const short8*)(pbase + lane * 16);          // kv 0..31
      short8 pf1 = *(const short8*)(pbase + 1024 + lane * 16);   // kv 32..63
      __builtin_amdgcn_s_setprio(1);
#pragma unroll
      for (int hf = 0; hf < 4; ++hf) {
        acc[hf] = __builtin_amdgcn_mfma_f32_16x16x32_bf16(pf0, va[hf], acc[hf], 0, 0, 0);
        acc[hf] = __builtin_amdgcn_mfma_f32_16x16x32_bf16(pf1, vb[hf], acc[hf], 0, 0, 0);
      }
      __builtin_amdgcn_s_setprio(0);
    }

    mcur = mnext;
    bar_vm0();                         // BAR2: all staging/mask complete
  }

  // ---- epilogue: l over 16 j-lanes, combine 4 kv-slices via lbuf
#pragma unroll
  for (int r = 0; r < 4; ++r) {
#pragma unroll
    for (int off = 1; off < 16; off <<= 1)
      lrow[r] += __shfl_xor(lrow[r], off, 64);
  }
  if (j == 0) {
#pragma unroll
    for (int r = 0; r < 4; ++r)
      lbuf[(qh * 16 + g * 4 + r) * 4 + kvs] = lrow[r];
  }
  __syncthreads();

#pragma unroll
  for (int rr = 0; rr < 4; ++rr) {
    int q = qp * 16 + rr * 4 + g;      // sigma-involution undone
    f32x4 lv = *(const f32x4*)&lbuf[q * 4];
    float linv = 1.0f / (lv[0] + lv[1] + lv[2] + lv[3]);
    float* orow = out + ((size_t)(b * S_LEN + m0 + q)) * DH + hs * 64 + j;
#pragma unroll
    for (int hf = 0; hf < 4; ++hf)
      orow[hf * 16] = acc[hf][rr] * linv;
  }
}

// ---------------------------------------------------------------------------
extern "C" void kernel_launch(void* const* d_in, const int* in_sizes, int n_in,
                              void* d_out, int out_size, void* d_ws, size_t ws_size,
                              hipStream_t stream) {
  const float* xq = (const float*)d_in[0];
  const float* xk = (const float*)d_in[1];
  const float* xv = (const float*)d_in[2];
  const int* mask = (const int*)d_in[3];
  const float* wq = (const float*)d_in[4];
  const float* bq = (const float*)d_in[5];
  const float* wk = (const float*)d_in[6];
  const float* bk = (const float*)d_in[7];
  const float* wv = (const float*)d_in[8];
  const float* bv = (const float*)d_in[9];
  float* out = (float*)d_out;

  char* ws = (char*)d_ws;
  unsigned short* wbf  = (unsigned short*)(ws);                    // 1.5 MB
  unsigned short* qbf  = (unsigned short*)(ws + (2ull  << 20));    // 8 MB
  unsigned short* kbf  = (unsigned short*)(ws + (10ull << 20));    // 8 MB
  unsigned short* vtbf = (unsigned short*)(ws + (18ull << 20));    // 8 MB

  hipLaunchKernelGGL(wcvt_kernel, dim3(768), dim3(256), 0, stream, wq, wk, wv, wbf);
  hipLaunchKernelGGL(proj_kernel, dim3(256, 1, 3), dim3(256), 0, stream,
                     xq, xk, xv, wbf, bq, bk, bv, qbf, kbf, vtbf);
  hipLaunchKernelGGL(attn_kernel, dim3(512), dim3(512), 0, stream,
                     qbf, kbf, vtbf, mask, out);
}

// Round 19
// 239.166 us; speedup vs baseline: 2.0382x; 2.0382x over previous
//
#include <hip/hip_runtime.h>
#include <cstdint>
#include <cstddef>

#define S_LEN 4096
#define DVEC  1024
#define DH    256

typedef __attribute__((ext_vector_type(8))) short short8;
typedef __attribute__((ext_vector_type(4))) float f32x4;
typedef __attribute__((ext_vector_type(4))) unsigned short ushort4v;

__device__ __forceinline__ unsigned short f2bf(float f) {
  unsigned u = __builtin_bit_cast(unsigned, f);
  u += 0x7FFFu + ((u >> 16) & 1u);          // round-to-nearest-even
  return (unsigned short)(u >> 16);
}

__device__ __forceinline__ void gl2lds16(const void* g, void* lds) {
  __builtin_amdgcn_global_load_lds(
      (const __attribute__((address_space(1))) unsigned int*)g,
      (__attribute__((address_space(3))) unsigned int*)lds, 16, 0, 0);
}

// Counted-vmcnt barrier (T4): waits only until <=N vmem ops remain in this
// wave's FIFO, so the NEXT tile's prefetch stays in flight across the
// barrier. N=12 = ops younger than the load the barrier must guarantee
// (4 gl2lds stage + 8 mask dwords issued after it).
__device__ __forceinline__ void wait_bar_12() {
  asm volatile("s_waitcnt vmcnt(12) lgkmcnt(0)" ::: "memory");
  __builtin_amdgcn_s_barrier();
  asm volatile("" ::: "memory");
}
__device__ __forceinline__ void wait_bar_0() {
  asm volatile("s_waitcnt vmcnt(0) lgkmcnt(0)" ::: "memory");
  __builtin_amdgcn_s_barrier();
  asm volatile("" ::: "memory");
}

// ---------------------------------------------------------------------------
// Kernel 1: weights f32 -> bf16 (wq pre-scaled by 1/sqrt(DH)=1/16).
// ---------------------------------------------------------------------------
__global__ void wcvt_kernel(const float* __restrict__ wq,
                            const float* __restrict__ wk,
                            const float* __restrict__ wv,
                            unsigned short* __restrict__ wbf) {
  int t   = blockIdx.x * 256 + threadIdx.x;
  int idx = t * 4;
  int m   = idx >> 18;
  int off = idx & 262143;
  const float* src = (m == 0) ? wq : (m == 1) ? wk : wv;
  float scale = (m == 0) ? 0.0625f : 1.0f;
  f32x4 v = *(const f32x4*)(src + off);
  ushort4v o;
  o.x = f2bf(v.x * scale);
  o.y = f2bf(v.y * scale);
  o.z = f2bf(v.z * scale);
  o.w = f2bf(v.w * scale);
  *(ushort4v*)(wbf + idx) = o;
}

// ---------------------------------------------------------------------------
// Kernel 2: projection GEMM. C = x * W^T + b -> bf16; z==2 stores V^T.
// ---------------------------------------------------------------------------
__global__ void proj_kernel(const float* __restrict__ xq,
                            const float* __restrict__ xk,
                            const float* __restrict__ xv,
                            const unsigned short* __restrict__ wbf,
                            const float* __restrict__ bq,
                            const float* __restrict__ bk,
                            const float* __restrict__ bv,
                            unsigned short* __restrict__ qbf,
                            unsigned short* __restrict__ kbf,
                            unsigned short* __restrict__ vtbf) {
  const int tid  = threadIdx.x;
  const int lane = tid & 63;
  const int w    = tid >> 6;
  const int z    = blockIdx.z;
  const int m0   = blockIdx.x * 64;

  const float* x = (z == 0) ? xq : (z == 1) ? xk : xv;
  const unsigned short* wz = wbf + (size_t)z * (DH * DVEC);
  const float* bias = (z == 0) ? bq : (z == 1) ? bk : bv;
  const float bscale = (z == 0) ? 0.0625f : 1.0f;

  __shared__ float At[2][64 * 32];

  f32x4 zero = {0.f, 0.f, 0.f, 0.f};
  f32x4 acc[4][4];
#pragma unroll
  for (int i = 0; i < 4; ++i)
#pragma unroll
    for (int j = 0; j < 4; ++j) acc[i][j] = zero;

  auto stage = [&](int kt, int buf) {
    char* dstb = (char*)&At[buf][0] + w * 2048;
#pragma unroll
    for (int i = 0; i < 2; ++i) {
      int lin  = w * 2048 + i * 1024 + lane * 16;
      int row  = lin >> 7;
      int scol = (lin ^ ((row & 7) << 4)) & 127;
      gl2lds16((const char*)x + ((size_t)(m0 + row) * DVEC + kt * 32) * 4 + scol,
               dstb + i * 1024);
    }
  };

  stage(0, 0);
  __syncthreads();

  for (int kt = 0; kt < 32; ++kt) {
    const int buf = kt & 1;
    if (kt + 1 < 32) stage(kt + 1, buf ^ 1);

    short8 bfr[4];
#pragma unroll
    for (int cf = 0; cf < 4; ++cf) {
      int h = w * 64 + cf * 16 + (lane & 15);
      int d = kt * 32 + (lane >> 4) * 8;
      bfr[cf] = *(const short8*)(wz + (size_t)h * DVEC + d);
    }
    const char* ab = (const char*)&At[buf][0];
#pragma unroll
    for (int rf = 0; rf < 4; ++rf) {
      int row = rf * 16 + (lane & 15);
      int c0  = row * 128 + (lane >> 4) * 32;
      int sw  = (row & 7) << 4;
      f32x4 v0 = *(const f32x4*)(ab + (c0 ^ sw));
      f32x4 v1 = *(const f32x4*)(ab + ((c0 + 16) ^ sw));
      short8 af;
      af[0] = (short)f2bf(v0.x); af[1] = (short)f2bf(v0.y);
      af[2] = (short)f2bf(v0.z); af[3] = (short)f2bf(v0.w);
      af[4] = (short)f2bf(v1.x); af[5] = (short)f2bf(v1.y);
      af[6] = (short)f2bf(v1.z); af[7] = (short)f2bf(v1.w);
#pragma unroll
      for (int cf = 0; cf < 4; ++cf)
        acc[rf][cf] = __builtin_amdgcn_mfma_f32_16x16x32_bf16(af, bfr[cf], acc[rf][cf], 0, 0, 0);
    }
    __syncthreads();
  }

  float bvv[4];
#pragma unroll
  for (int cf = 0; cf < 4; ++cf)
    bvv[cf] = bias[w * 64 + cf * 16 + (lane & 15)] * bscale;

  if (z < 2) {
    unsigned short* o = (z == 0) ? qbf : kbf;
#pragma unroll
    for (int rf = 0; rf < 4; ++rf)
#pragma unroll
      for (int cf = 0; cf < 4; ++cf)
#pragma unroll
        for (int r = 0; r < 4; ++r) {
          int m = m0 + rf * 16 + (lane >> 4) * 4 + r;
          int h = w * 64 + cf * 16 + (lane & 15);
          o[(size_t)m * DH + h] = f2bf(acc[rf][cf][r] + bvv[cf]);
        }
  } else {
    int bb = m0 >> 12;
    int sl = m0 & 4095;
#pragma unroll
    for (int rf = 0; rf < 4; ++rf)
#pragma unroll
      for (int cf = 0; cf < 4; ++cf) {
        int s = sl + rf * 16 + (lane >> 4) * 4;
        int h = w * 64 + cf * 16 + (lane & 15);
        ushort4v o;
        o.x = f2bf(acc[rf][cf][0] + bvv[cf]);
        o.y = f2bf(acc[rf][cf][1] + bvv[cf]);
        o.z = f2bf(acc[rf][cf][2] + bvv[cf]);
        o.w = f2bf(acc[rf][cf][3] + bvv[cf]);
        *(ushort4v*)(vtbf + ((size_t)(bb * DH + h)) * S_LEN + s) = o;
      }
  }
}

// ---------------------------------------------------------------------------
// Kernel 3: fused masked attention — the verified best (round-12): r4
// structure with counted-vmcnt barriers (T4).
// Per-iteration vmem program order: stageK(t+1) 4 gl2lds -> mask 8 dwords ->
// [QK, softmax, P] -> BAR1(vmcnt 12: drains stageV(t), keeps newer 12) ->
// stageV(t+1) 4 gl2lds -> [PV] -> BAR2(vmcnt 12: drains stageK(t+1)).
// Block = 64 q rows, KVB = 64, 8 waves.
//   QK role:  wave w -> (kvs = w&3: 16-kv slice, qh = w>>2: 32 q rows)
//   PV role:  wave w -> (qs = w>>2: 32 q rows,  hs = w&3: 64 h cols)
// Softmax without max (scores bounded; exp(0)=1 matches reference fill-0).
// LDS: K 2x32KB | V 2x32KB | P 8KB | l 1KB = 140288 bytes.
// ---------------------------------------------------------------------------
__global__ void __launch_bounds__(512, 2)
attn_kernel(const unsigned short* __restrict__ qbf,
            const unsigned short* __restrict__ kbf,
            const unsigned short* __restrict__ vtbf,
            const int* __restrict__ mask,
            float* __restrict__ out) {
  const int tid  = threadIdx.x;
  const int lane = tid & 63;
  const int w    = tid >> 6;          // 0..7
  const int j    = lane & 15;
  const int g    = lane >> 4;

  const int kvs = w & 3;              // QK role
  const int qh  = w >> 2;
  const int qs  = w >> 2;             // PV role
  const int hs  = w & 3;

  // XCD-aware decode (blocks on one XCD share a batch -> K/V L2-resident)
  const int bx = blockIdx.x;
  const int x  = bx & 7;
  const int b  = x >> 1;
  const int qt = (bx >> 3) * 2 + (x & 1);
  const int m0 = qt * 64;

  __shared__ char sbuf[140288];
  // K: buf*32768 ; V: 65536 + buf*32768 ; P: 131072 ; l: 139264

  // ---- Q fragments: rows qh*32 + qf*16 + j, k-chunks kc (h = kc*32 + g*8)
  short8 qreg[2][8];
#pragma unroll
  for (int qf = 0; qf < 2; ++qf) {
    const unsigned short* qrow =
        qbf + ((size_t)(b * S_LEN + m0 + qh * 32 + qf * 16 + j)) * DH + g * 8;
#pragma unroll
    for (int kc = 0; kc < 8; ++kc) qreg[qf][kc] = *(const short8*)(qrow + kc * 32);
  }

  f32x4 zero = {0.f, 0.f, 0.f, 0.f};
  f32x4 acc[2][4];
#pragma unroll
  for (int a = 0; a < 2; ++a)
#pragma unroll
    for (int hf = 0; hf < 4; ++hf) acc[a][hf] = zero;
  float lrow[2][4] = {{0.f, 0.f, 0.f, 0.f}, {0.f, 0.f, 0.f, 0.f}};

  // raw mask: q = m0 + qh*32 + g*4 + qf*16 + r ; kv = t*64 + kvs*16 + j
  const int* mb = mask + ((size_t)(b * S_LEN + m0 + qh * 32 + g * 4)) * S_LEN + kvs * 16 + j;

  // ---- staging: 32 chunks of 1KB each, 4 per wave, wave-uniform LDS dst
  auto stageK = [&](int t, int buf) {
    const char* src = (const char*)kbf + ((size_t)(b * S_LEN) + t * 64) * 512;
    char* dst = sbuf + buf * 32768 + w * 4096;
#pragma unroll
    for (int i = 0; i < 4; ++i) {
      int rid = w * 4 + i;            // (ks = rid>>3, kc = rid&7)
      int ks  = rid >> 3;
      int kc  = rid & 7;
      gl2lds16(src + (size_t)(ks * 16 + j) * 512 + kc * 64 + g * 16, dst + i * 1024);
    }
  };
  auto stageV = [&](int t, int buf) {
    char* dst = sbuf + 65536 + buf * 32768 + w * 4096;
#pragma unroll
    for (int i = 0; i < 4; ++i) {
      int rid = w * 4 + i;            // (h16 = rid>>1, kc2 = rid&1)
      int h16 = rid >> 1;
      int kc2 = rid & 1;
      const char* src = (const char*)vtbf +
          (((size_t)(b * DH + h16 * 16 + j)) * S_LEN + t * 64 + kc2 * 32 + g * 8) * 2;
      gl2lds16(src, dst + i * 1024);
    }
  };

  int mcur[8], mnext[8];
#pragma unroll
  for (int qf = 0; qf < 2; ++qf)
#pragma unroll
    for (int r = 0; r < 4; ++r) mcur[qf * 4 + r] = mb[(qf * 16 + r) * S_LEN];
  stageK(0, 0);
  stageV(0, 0);
  __syncthreads();

  // P-write base: chunk (qi*2 + kvs>>1), slot fields: g2 = (kvs&1)*2 + (j>>3),
  // row' = r*4+g (involution), byte low = (j&7)*2
  const int pwbase = 131072 + (kvs >> 1) * 1024 + ((kvs & 1) * 2 + (j >> 3)) * 256 + (j & 7) * 2;

  const int NT = S_LEN / 64;   // 64
  for (int t = 0; t < NT; ++t) {
    const int buf = t & 1;
    if (t + 1 < NT) {
      stageK(t + 1, buf ^ 1);          // 4 gl2lds, stays in flight past BAR1
#pragma unroll
      for (int qf = 0; qf < 2; ++qf)
#pragma unroll
        for (int r = 0; r < 4; ++r)
          mnext[qf * 4 + r] = mb[(qf * 16 + r) * S_LEN + (t + 1) * 64];
    }

    // ---- QK: sc = Q(32q) x K-slice(16kv), 4 interleaved MFMA chains
    const char* kb = sbuf + buf * 32768 + kvs * 8192;
    f32x4 s0[2], s1[2];
    s0[0] = zero; s0[1] = zero; s1[0] = zero; s1[1] = zero;
    __builtin_amdgcn_s_setprio(1);
#pragma unroll
    for (int kc = 0; kc < 8; kc += 2) {
      short8 k0 = *(const short8*)(kb + kc * 1024 + lane * 16);
      short8 k1 = *(const short8*)(kb + (kc + 1) * 1024 + lane * 16);
      s0[0] = __builtin_amdgcn_mfma_f32_16x16x32_bf16(qreg[0][kc], k0, s0[0], 0, 0, 0);
      s0[1] = __builtin_amdgcn_mfma_f32_16x16x32_bf16(qreg[1][kc], k0, s0[1], 0, 0, 0);
      s1[0] = __builtin_amdgcn_mfma_f32_16x16x32_bf16(qreg[0][kc + 1], k1, s1[0], 0, 0, 0);
      s1[1] = __builtin_amdgcn_mfma_f32_16x16x32_bf16(qreg[1][kc + 1], k1, s1[1], 0, 0, 0);
    }
    __builtin_amdgcn_s_setprio(0);

    // ---- softmax (no max): p = mask ? exp(s) : 1 ; write P (bf16)
#pragma unroll
    for (int qf = 0; qf < 2; ++qf) {
      int cb = pwbase + (qh * 2 + qf) * 2048;
#pragma unroll
      for (int r = 0; r < 4; ++r) {
        float sv = s0[qf][r] + s1[qf][r];
        sv = mcur[qf * 4 + r] ? sv : 0.0f;
        float e = __expf(sv);
        lrow[qf][r] += e;
        *(unsigned short*)(sbuf + cb + (r * 4 + g) * 16) = f2bf(e);
      }
    }

    // BAR1: drains stageV(t) (12 younger ops stay in flight); P visible.
    if (t + 1 < NT) wait_bar_12(); else wait_bar_0();

    if (t + 1 < NT) stageV(t + 1, buf ^ 1);  // 4 gl2lds, in flight past BAR2

    // ---- PV: O(32q x 64h) += P(32q x 64kv) x V(64kv x 64h)
    const char* vb = sbuf + 65536 + buf * 32768 + hs * 8192;
    short8 pf[2][2];
#pragma unroll
    for (int qf2 = 0; qf2 < 2; ++qf2)
#pragma unroll
      for (int kc2 = 0; kc2 < 2; ++kc2)
        pf[qf2][kc2] = *(const short8*)(sbuf + 131072 + ((qs * 2 + qf2) * 2 + kc2) * 1024 + lane * 16);
    __builtin_amdgcn_s_setprio(1);
#pragma unroll
    for (int hf = 0; hf < 4; ++hf) {
      short8 v0 = *(const short8*)(vb + (hf * 2 + 0) * 1024 + lane * 16);
      short8 v1 = *(const short8*)(vb + (hf * 2 + 1) * 1024 + lane * 16);
      acc[0][hf] = __builtin_amdgcn_mfma_f32_16x16x32_bf16(pf[0][0], v0, acc[0][hf], 0, 0, 0);
      acc[1][hf] = __builtin_amdgcn_mfma_f32_16x16x32_bf16(pf[1][0], v0, acc[1][hf], 0, 0, 0);
      acc[0][hf] = __builtin_amdgcn_mfma_f32_16x16x32_bf16(pf[0][1], v1, acc[0][hf], 0, 0, 0);
      acc[1][hf] = __builtin_amdgcn_mfma_f32_16x16x32_bf16(pf[1][1], v1, acc[1][hf], 0, 0, 0);
    }
    __builtin_amdgcn_s_setprio(0);

#pragma unroll
    for (int i = 0; i < 8; ++i) mcur[i] = mnext[i];

    // BAR2: drains stageK(t+1) (12 younger ops stay in flight); P consumed.
    if (t + 1 < NT) wait_bar_12(); else wait_bar_0();
  }

  // ---- epilogue: reduce l over 16 j-lanes, exchange 4 kv-slices via LDS
#pragma unroll
  for (int qf = 0; qf < 2; ++qf)
#pragma unroll
    for (int r = 0; r < 4; ++r) {
#pragma unroll
      for (int off = 1; off < 16; off <<= 1)
        lrow[qf][r] += __shfl_xor(lrow[qf][r], off, 64);
    }
  float* lbuf = (float*)(sbuf + 139264);   // [64][4]
  if (j == 0) {
#pragma unroll
    for (int qf = 0; qf < 2; ++qf)
#pragma unroll
      for (int r = 0; r < 4; ++r)
        lbuf[(qh * 32 + qf * 16 + g * 4 + r) * 4 + kvs] = lrow[qf][r];
  }
  __syncthreads();

#pragma unroll
  for (int qf2 = 0; qf2 < 2; ++qf2)
#pragma unroll
    for (int rr = 0; rr < 4; ++rr) {
      int qb = qs * 32 + qf2 * 16 + rr * 4 + g;   // physical q (involution undone)
      f32x4 lv = *(const f32x4*)&lbuf[qb * 4];
      float linv = 1.0f / (lv[0] + lv[1] + lv[2] + lv[3]);
      float* orow = out + ((size_t)(b * S_LEN + m0 + qb)) * DH + hs * 64 + j;
#pragma unroll
      for (int hf = 0; hf < 4; ++hf)
        orow[hf * 16] = acc[qf2][hf][rr] * linv;
    }
}

// ---------------------------------------------------------------------------
extern "C" void kernel_launch(void* const* d_in, const int* in_sizes, int n_in,
                              void* d_out, int out_size, void* d_ws, size_t ws_size,
                              hipStream_t stream) {
  const float* xq = (const float*)d_in[0];
  const float* xk = (const float*)d_in[1];
  const float* xv = (const float*)d_in[2];
  const int* mask = (const int*)d_in[3];
  const float* wq = (const float*)d_in[4];
  const float* bq = (const float*)d_in[5];
  const float* wk = (const float*)d_in[6];
  const float* bk = (const float*)d_in[7];
  const float* wv = (const float*)d_in[8];
  const float* bv = (const float*)d_in[9];
  float* out = (float*)d_out;

  char* ws = (char*)d_ws;
  unsigned short* wbf  = (unsigned short*)(ws);                    // 1.5 MB
  unsigned short* qbf  = (unsigned short*)(ws + (2ull  << 20));    // 8 MB
  unsigned short* kbf  = (unsigned short*)(ws + (10ull << 20));    // 8 MB
  unsigned short* vtbf = (unsigned short*)(ws + (18ull << 20));    // 8 MB

  hipLaunchKernelGGL(wcvt_kernel, dim3(768), dim3(256), 0, stream, wq, wk, wv, wbf);
  hipLaunchKernelGGL(proj_kernel, dim3(256, 1, 3), dim3(256), 0, stream,
                     xq, xk, xv, wbf, bq, bk, bv, qbf, kbf, vtbf);
  hipLaunchKernelGGL(attn_kernel, dim3(256), dim3(512), 0, stream,
                     qbf, kbf, vtbf, mask, out);
}